// Round 1
// baseline (100.835 us; speedup 1.0000x reference)
//
#include <hip/hip_runtime.h>

#define BATCH 4
#define NPTS  8192
#define QPT   4          // queries per thread
#define CH    1024       // candidate chunk size
#define NCH   (NPTS / CH)          // 8 chunks
#define QBLK  (NPTS / (256 * QPT)) // 8 query-blocks per batch

// ---------------- pack: (B*N,3) f32 -> (B*N) float4 {x,y,z,|p|^2} ----------
__global__ void pack_kernel(const float* __restrict__ preds,
                            const float* __restrict__ gts,
                            float4* __restrict__ packP,
                            float4* __restrict__ packG) {
    int i = blockIdx.x * blockDim.x + threadIdx.x;
    const float* src = (blockIdx.y == 0) ? preds : gts;
    float4* dst      = (blockIdx.y == 0) ? packP : packG;
    if (i < BATCH * NPTS) {
        float x = src[3 * i], y = src[3 * i + 1], z = src[3 * i + 2];
        dst[i] = make_float4(x, y, z, x * x + y * y + z * z);
    }
}

// ---------------- main: per-(dir,chunk) partial min over candidates --------
// grid: (BATCH*QBLK, NCH, 2); block: 256
// partial layout: [dir][chunk][B*N]
__global__ void __launch_bounds__(256)
chamfer_min_kernel(const float4* __restrict__ packP,
                   const float4* __restrict__ packG,
                   float* __restrict__ partial) {
    const int dir   = blockIdx.z;   // 0: queries=preds, cand=gts ; 1: swapped
    const int chunk = blockIdx.y;
    const int b     = blockIdx.x / QBLK;
    const int qb    = blockIdx.x % QBLK;
    const int t     = threadIdx.x;

    const float4* __restrict__ qp = (dir == 0) ? packP : packG;
    const float4* __restrict__ cp = (dir == 0) ? packG : packP;

    const int qbase = b * NPTS + qb * (256 * QPT) + t;

    float qx[QPT], qy[QPT], qz[QPT], m[QPT];
#pragma unroll
    for (int k = 0; k < QPT; ++k) {
        float4 v = qp[qbase + k * 256];
        qx[k] = v.x; qy[k] = v.y; qz[k] = v.z;
        m[k] = 1e30f;
    }

    const float4* __restrict__ cbase = cp + b * NPTS + chunk * CH;
#pragma unroll 8
    for (int c = 0; c < CH; ++c) {
        float4 cv = cbase[c];          // wave-uniform -> scalar load
#pragma unroll
        for (int k = 0; k < QPT; ++k) {
            float dot = fmaf(qz[k], cv.z, fmaf(qy[k], cv.y, qx[k] * cv.x));
            m[k] = fminf(m[k], fmaf(-2.0f, dot, cv.w));
        }
    }

    float* __restrict__ pout = partial + (size_t)(dir * NCH + chunk) * (BATCH * NPTS);
#pragma unroll
    for (int k = 0; k < QPT; ++k)
        pout[qbase + k * 256] = m[k];
}

// ---------------- finalize: min over chunks, + qsq, global sum -------------
// grid: 2*B*N/256 = 256 blocks
__global__ void __launch_bounds__(256)
finalize_kernel(const float* __restrict__ partial,
                const float4* __restrict__ packP,
                const float4* __restrict__ packG,
                float* __restrict__ out) {
    __shared__ float red[4];
    const int idx = blockIdx.x * 256 + threadIdx.x;   // [0, 2*B*N)
    const int dir = idx / (BATCH * NPTS);
    const int q   = idx % (BATCH * NPTS);

    float mn = 1e30f;
#pragma unroll
    for (int c = 0; c < NCH; ++c)
        mn = fminf(mn, partial[(size_t)(dir * NCH + c) * (BATCH * NPTS) + q]);

    const float qsq = ((dir == 0) ? packP : packG)[q].w;
    float val = mn + qsq;

#pragma unroll
    for (int off = 32; off > 0; off >>= 1)
        val += __shfl_down(val, off, 64);

    const int wave = threadIdx.x >> 6;
    const int lane = threadIdx.x & 63;
    if (lane == 0) red[wave] = val;
    __syncthreads();
    if (threadIdx.x == 0)
        atomicAdd(out, red[0] + red[1] + red[2] + red[3]);
}

extern "C" void kernel_launch(void* const* d_in, const int* in_sizes, int n_in,
                              void* d_out, int out_size, void* d_ws, size_t ws_size,
                              hipStream_t stream) {
    const float* preds = (const float*)d_in[0];
    const float* gts   = (const float*)d_in[1];
    float* out = (float*)d_out;

    // workspace layout
    char* ws = (char*)d_ws;
    float4* packP   = (float4*)ws;                                  // 512 KB
    float4* packG   = (float4*)(ws + (size_t)BATCH * NPTS * 16);    // 512 KB
    float*  partial = (float*)(ws + (size_t)2 * BATCH * NPTS * 16); // 2 MB

    dim3 gpack((BATCH * NPTS + 255) / 256, 2);
    pack_kernel<<<gpack, 256, 0, stream>>>(preds, gts, packP, packG);

    dim3 gmain(BATCH * QBLK, NCH, 2);
    chamfer_min_kernel<<<gmain, 256, 0, stream>>>(packP, packG, partial);

    hipMemsetAsync(out, 0, sizeof(float), stream);

    finalize_kernel<<<2 * BATCH * NPTS / 256, 256, 0, stream>>>(partial, packP, packG, out);
}

// Round 2
// 78.910 us; speedup vs baseline: 1.2778x; 1.2778x over previous
//
#include <hip/hip_runtime.h>

#define BATCH 4
#define NPTS  8192
#define QPT   4                    // queries per thread
#define CH    512                  // candidate chunk size
#define NCH   (NPTS / CH)          // 16 chunks
#define QBLK  (NPTS / (256 * QPT)) // 8 query-blocks per batch

// ---- pack: (B*N,3) f32 -> (B*N) float4 {-2x, -2y, -2z, |p|^2} -------------
__global__ void pack_kernel(const float* __restrict__ preds,
                            const float* __restrict__ gts,
                            float4* __restrict__ packP,
                            float4* __restrict__ packG) {
    int i = blockIdx.x * blockDim.x + threadIdx.x;
    const float* src = (blockIdx.y == 0) ? preds : gts;
    float4* dst      = (blockIdx.y == 0) ? packP : packG;
    if (i < BATCH * NPTS) {
        float x = src[3 * i], y = src[3 * i + 1], z = src[3 * i + 2];
        dst[i] = make_float4(-2.0f * x, -2.0f * y, -2.0f * z,
                             x * x + y * y + z * z);
    }
}

// ---- main: per-(dir,chunk) partial min over candidates --------------------
// grid: (BATCH*QBLK, NCH, 2); block: 256
// partial layout: [dir][chunk][B*N]
__global__ void __launch_bounds__(256, 4)
chamfer_min_kernel(const float4* __restrict__ packP,
                   const float4* __restrict__ packG,
                   float* __restrict__ partial) {
    const int dir   = blockIdx.z;   // 0: queries=preds, cand=gts ; 1: swapped
    const int chunk = blockIdx.y;
    const int b     = blockIdx.x / QBLK;
    const int qb    = blockIdx.x % QBLK;
    const int t     = threadIdx.x;

    const float4* __restrict__ qp = (dir == 0) ? packP : packG;
    const float4* __restrict__ cp = (dir == 0) ? packG : packP;

    const int qbase = b * NPTS + qb * (256 * QPT) + t;

    float qx[QPT], qy[QPT], qz[QPT], m[QPT];
#pragma unroll
    for (int k = 0; k < QPT; ++k) {
        float4 v = qp[qbase + k * 256];       // scaled array; recover raw q
        qx[k] = -0.5f * v.x;
        qy[k] = -0.5f * v.y;
        qz[k] = -0.5f * v.z;
        m[k] = 1e30f;
    }

    const float4* __restrict__ cbase = cp + b * NPTS + chunk * CH;
#pragma unroll 4
    for (int c = 0; c < CH; c += 2) {
        float4 c0 = cbase[c];                 // wave-uniform loads
        float4 c1 = cbase[c + 1];
#pragma unroll
        for (int k = 0; k < QPT; ++k) {
            float d0 = fmaf(qx[k], c0.x, fmaf(qy[k], c0.y, fmaf(qz[k], c0.z, c0.w)));
            float d1 = fmaf(qx[k], c1.x, fmaf(qy[k], c1.y, fmaf(qz[k], c1.z, c1.w)));
            m[k] = fminf(m[k], fminf(d0, d1));   // -> v_min3_f32
        }
    }

    float* __restrict__ pout = partial + (size_t)(dir * NCH + chunk) * (BATCH * NPTS);
#pragma unroll
    for (int k = 0; k < QPT; ++k)
        pout[qbase + k * 256] = m[k];
}

// ---- finalize: min over chunks, + qsq, global sum -------------------------
// grid: 2*B*N/256 = 256 blocks
__global__ void __launch_bounds__(256)
finalize_kernel(const float* __restrict__ partial,
                const float4* __restrict__ packP,
                const float4* __restrict__ packG,
                float* __restrict__ out) {
    __shared__ float red[4];
    const int idx = blockIdx.x * 256 + threadIdx.x;   // [0, 2*B*N)
    const int dir = idx / (BATCH * NPTS);
    const int q   = idx % (BATCH * NPTS);

    float mn = 1e30f;
#pragma unroll
    for (int c = 0; c < NCH; ++c)
        mn = fminf(mn, partial[(size_t)(dir * NCH + c) * (BATCH * NPTS) + q]);

    const float qsq = ((dir == 0) ? packP : packG)[q].w;
    float val = mn + qsq;

#pragma unroll
    for (int off = 32; off > 0; off >>= 1)
        val += __shfl_down(val, off, 64);

    const int wave = threadIdx.x >> 6;
    const int lane = threadIdx.x & 63;
    if (lane == 0) red[wave] = val;
    __syncthreads();
    if (threadIdx.x == 0)
        atomicAdd(out, red[0] + red[1] + red[2] + red[3]);
}

extern "C" void kernel_launch(void* const* d_in, const int* in_sizes, int n_in,
                              void* d_out, int out_size, void* d_ws, size_t ws_size,
                              hipStream_t stream) {
    const float* preds = (const float*)d_in[0];
    const float* gts   = (const float*)d_in[1];
    float* out = (float*)d_out;

    // workspace layout: packs 1 MB, partial 4 MB
    char* ws = (char*)d_ws;
    float4* packP   = (float4*)ws;                                  // 512 KB
    float4* packG   = (float4*)(ws + (size_t)BATCH * NPTS * 16);    // 512 KB
    float*  partial = (float*)(ws + (size_t)2 * BATCH * NPTS * 16); // 4 MB

    dim3 gpack((BATCH * NPTS + 255) / 256, 2);
    pack_kernel<<<gpack, 256, 0, stream>>>(preds, gts, packP, packG);

    dim3 gmain(BATCH * QBLK, NCH, 2);
    chamfer_min_kernel<<<gmain, 256, 0, stream>>>(packP, packG, partial);

    hipMemsetAsync(out, 0, sizeof(float), stream);

    finalize_kernel<<<2 * BATCH * NPTS / 256, 256, 0, stream>>>(partial, packP, packG, out);
}

// Round 3
// 78.510 us; speedup vs baseline: 1.2844x; 1.0051x over previous
//
#include <hip/hip_runtime.h>

#define BATCH 4
#define NPTS  8192
#define BN    (BATCH * NPTS)
#define QPT   4                    // queries per thread
#define CH    256                  // candidate chunk size
#define NCH   (NPTS / CH)          // 32 chunks
#define QBLK  (NPTS / (256 * QPT)) // 8 query-blocks per batch

// order-preserving float <-> uint for unsigned atomicMin
__device__ __forceinline__ unsigned fkey(float f) {
    unsigned u = __float_as_uint(f);
    return u ^ (unsigned)(((int)u >> 31) | 0x80000000);
}
__device__ __forceinline__ float funkey(unsigned k) {
    unsigned u = k ^ ((k & 0x80000000u) ? 0x80000000u : 0xFFFFFFFFu);
    return __uint_as_float(u);
}

// ---- pack: (B*N,3) f32 -> (B*N) float4 {-2x, -2y, -2z, |p|^2} -------------
__global__ void pack_kernel(const float* __restrict__ preds,
                            const float* __restrict__ gts,
                            float4* __restrict__ packP,
                            float4* __restrict__ packG) {
    int i = blockIdx.x * blockDim.x + threadIdx.x;
    const float* src = (blockIdx.y == 0) ? preds : gts;
    float4* dst      = (blockIdx.y == 0) ? packP : packG;
    if (i < BN) {
        float x = src[3 * i], y = src[3 * i + 1], z = src[3 * i + 2];
        dst[i] = make_float4(-2.0f * x, -2.0f * y, -2.0f * z,
                             x * x + y * y + z * z);
    }
}

// ---- main: min over candidate chunk, atomicMin into key array -------------
// grid: (BATCH*QBLK, NCH, 2); block: 256
// keys layout: [dir][B*N], encoded min of (csq - 2<q,c>)
__global__ void __launch_bounds__(256, 8)
chamfer_min_kernel(const float4* __restrict__ packP,
                   const float4* __restrict__ packG,
                   unsigned* __restrict__ keys) {
    const int dir   = blockIdx.z;   // 0: queries=preds, cand=gts ; 1: swapped
    const int chunk = blockIdx.y;
    const int b     = blockIdx.x / QBLK;
    const int qb    = blockIdx.x % QBLK;
    const int t     = threadIdx.x;

    const float4* __restrict__ qp = (dir == 0) ? packP : packG;
    const float4* __restrict__ cp = (dir == 0) ? packG : packP;

    const int qbase = b * NPTS + qb * (256 * QPT) + t;

    float qx[QPT], qy[QPT], qz[QPT], m[QPT];
#pragma unroll
    for (int k = 0; k < QPT; ++k) {
        float4 v = qp[qbase + k * 256];       // scaled array; recover raw q
        qx[k] = -0.5f * v.x;
        qy[k] = -0.5f * v.y;
        qz[k] = -0.5f * v.z;
        m[k] = 1e30f;
    }

    const float4* __restrict__ cbase = cp + b * NPTS + chunk * CH;
#pragma unroll 8
    for (int c = 0; c < CH; c += 2) {
        float4 c0 = cbase[c];                 // wave-uniform loads
        float4 c1 = cbase[c + 1];
#pragma unroll
        for (int k = 0; k < QPT; ++k) {
            float d0 = fmaf(qx[k], c0.x, fmaf(qy[k], c0.y, fmaf(qz[k], c0.z, c0.w)));
            float d1 = fmaf(qx[k], c1.x, fmaf(qy[k], c1.y, fmaf(qz[k], c1.z, c1.w)));
            m[k] = fminf(m[k], fminf(d0, d1));   // -> v_min3_f32
        }
    }

    unsigned* __restrict__ kout = keys + (size_t)dir * BN;
#pragma unroll
    for (int k = 0; k < QPT; ++k)
        atomicMin(&kout[qbase + k * 256], fkey(m[k]));
}

// ---- finalize: decode key, + qsq, global sum ------------------------------
// grid: 2*B*N/256 = 256 blocks
__global__ void __launch_bounds__(256)
finalize_kernel(const unsigned* __restrict__ keys,
                const float4* __restrict__ packP,
                const float4* __restrict__ packG,
                float* __restrict__ out) {
    __shared__ float red[4];
    const int idx = blockIdx.x * 256 + threadIdx.x;   // [0, 2*B*N)
    const int dir = idx / BN;
    const int q   = idx % BN;

    const float mn  = funkey(keys[idx]);
    const float qsq = ((dir == 0) ? packP : packG)[q].w;
    float val = mn + qsq;

#pragma unroll
    for (int off = 32; off > 0; off >>= 1)
        val += __shfl_down(val, off, 64);

    const int wave = threadIdx.x >> 6;
    const int lane = threadIdx.x & 63;
    if (lane == 0) red[wave] = val;
    __syncthreads();
    if (threadIdx.x == 0)
        atomicAdd(out, red[0] + red[1] + red[2] + red[3]);
}

extern "C" void kernel_launch(void* const* d_in, const int* in_sizes, int n_in,
                              void* d_out, int out_size, void* d_ws, size_t ws_size,
                              hipStream_t stream) {
    const float* preds = (const float*)d_in[0];
    const float* gts   = (const float*)d_in[1];
    float* out = (float*)d_out;

    // workspace layout: packs 1 MB, keys 256 KB
    char* ws = (char*)d_ws;
    float4*   packP = (float4*)ws;                                // 512 KB
    float4*   packG = (float4*)(ws + (size_t)BN * 16);            // 512 KB
    unsigned* keys  = (unsigned*)(ws + (size_t)2 * BN * 16);      // 256 KB

    dim3 gpack((BN + 255) / 256, 2);
    pack_kernel<<<gpack, 256, 0, stream>>>(preds, gts, packP, packG);

    hipMemsetAsync(keys, 0xFF, (size_t)2 * BN * sizeof(unsigned), stream);
    hipMemsetAsync(out, 0, sizeof(float), stream);

    dim3 gmain(BATCH * QBLK, NCH, 2);
    chamfer_min_kernel<<<gmain, 256, 0, stream>>>(packP, packG, keys);

    finalize_kernel<<<2 * BN / 256, 256, 0, stream>>>(keys, packP, packG, out);
}

// Round 4
// 58.924 us; speedup vs baseline: 1.7113x; 1.3324x over previous
//
#include <hip/hip_runtime.h>

#define BATCH 4
#define NPTS  8192
#define BN    (BATCH * NPTS)
#define QPT   4                    // queries per thread
#define CH    256                  // candidate chunk size (== blockDim)
#define NCH   (NPTS / CH)          // 32 chunks
#define QBLK  (NPTS / (256 * QPT)) // 8 query-blocks per batch

// order-preserving float <-> uint for unsigned atomicMin
__device__ __forceinline__ unsigned fkey(float f) {
    unsigned u = __float_as_uint(f);
    return u ^ (unsigned)(((int)u >> 31) | 0x80000000);
}
__device__ __forceinline__ float funkey(unsigned k) {
    unsigned u = k ^ ((k & 0x80000000u) ? 0x80000000u : 0xFFFFFFFFu);
    return __uint_as_float(u);
}

// ---- pack: (B*N,3) f32 -> (B*N) float4 {-2x, -2y, -2z, |p|^2} -------------
__global__ void pack_kernel(const float* __restrict__ preds,
                            const float* __restrict__ gts,
                            float4* __restrict__ packP,
                            float4* __restrict__ packG) {
    int i = blockIdx.x * blockDim.x + threadIdx.x;
    const float* src = (blockIdx.y == 0) ? preds : gts;
    float4* dst      = (blockIdx.y == 0) ? packP : packG;
    if (i < BN) {
        float x = src[3 * i], y = src[3 * i + 1], z = src[3 * i + 2];
        dst[i] = make_float4(-2.0f * x, -2.0f * y, -2.0f * z,
                             x * x + y * y + z * z);
    }
}

// ---- main: LDS-staged candidates, min over chunk, atomicMin into keys -----
// grid: (BATCH*QBLK, NCH, 2); block: 256
__global__ void __launch_bounds__(256, 4)
chamfer_min_kernel(const float4* __restrict__ packP,
                   const float4* __restrict__ packG,
                   unsigned* __restrict__ keys) {
    __shared__ float4 cl[CH];

    const int dir   = blockIdx.z;   // 0: queries=preds, cand=gts ; 1: swapped
    const int chunk = blockIdx.y;
    const int b     = blockIdx.x / QBLK;
    const int qb    = blockIdx.x % QBLK;
    const int t     = threadIdx.x;

    const float4* __restrict__ qp = (dir == 0) ? packP : packG;
    const float4* __restrict__ cp = (dir == 0) ? packG : packP;

    // stage candidate chunk into LDS (one coalesced float4 per thread)
    cl[t] = cp[b * NPTS + chunk * CH + t];

    const int qbase = b * NPTS + qb * (256 * QPT) + t;

    float qx[QPT], qy[QPT], qz[QPT], m[QPT];
#pragma unroll
    for (int k = 0; k < QPT; ++k) {
        float4 v = qp[qbase + k * 256];       // scaled array; recover raw q
        qx[k] = -0.5f * v.x;
        qy[k] = -0.5f * v.y;
        qz[k] = -0.5f * v.z;
        m[k] = 1e30f;
    }

    __syncthreads();

#pragma unroll 4
    for (int c = 0; c < CH; c += 2) {
        float4 c0 = cl[c];        // uniform address -> LDS broadcast, no conflict
        float4 c1 = cl[c + 1];
#pragma unroll
        for (int k = 0; k < QPT; ++k) {
            float d0 = fmaf(qx[k], c0.x, fmaf(qy[k], c0.y, fmaf(qz[k], c0.z, c0.w)));
            float d1 = fmaf(qx[k], c1.x, fmaf(qy[k], c1.y, fmaf(qz[k], c1.z, c1.w)));
            m[k] = fminf(m[k], fminf(d0, d1));   // -> v_min3_f32
        }
    }

    unsigned* __restrict__ kout = keys + (size_t)dir * BN;
#pragma unroll
    for (int k = 0; k < QPT; ++k)
        atomicMin(&kout[qbase + k * 256], fkey(m[k]));
}

// ---- finalize: decode key, + qsq, global sum ------------------------------
// grid: 2*B*N/256 = 256 blocks
__global__ void __launch_bounds__(256)
finalize_kernel(const unsigned* __restrict__ keys,
                const float4* __restrict__ packP,
                const float4* __restrict__ packG,
                float* __restrict__ out) {
    __shared__ float red[4];
    const int idx = blockIdx.x * 256 + threadIdx.x;   // [0, 2*B*N)
    const int dir = idx / BN;
    const int q   = idx % BN;

    const float mn  = funkey(keys[idx]);
    const float qsq = ((dir == 0) ? packP : packG)[q].w;
    float val = mn + qsq;

#pragma unroll
    for (int off = 32; off > 0; off >>= 1)
        val += __shfl_down(val, off, 64);

    const int wave = threadIdx.x >> 6;
    const int lane = threadIdx.x & 63;
    if (lane == 0) red[wave] = val;
    __syncthreads();
    if (threadIdx.x == 0)
        atomicAdd(out, red[0] + red[1] + red[2] + red[3]);
}

extern "C" void kernel_launch(void* const* d_in, const int* in_sizes, int n_in,
                              void* d_out, int out_size, void* d_ws, size_t ws_size,
                              hipStream_t stream) {
    const float* preds = (const float*)d_in[0];
    const float* gts   = (const float*)d_in[1];
    float* out = (float*)d_out;

    // workspace layout: packs 1 MB, keys 256 KB
    char* ws = (char*)d_ws;
    float4*   packP = (float4*)ws;                                // 512 KB
    float4*   packG = (float4*)(ws + (size_t)BN * 16);            // 512 KB
    unsigned* keys  = (unsigned*)(ws + (size_t)2 * BN * 16);      // 256 KB

    dim3 gpack((BN + 255) / 256, 2);
    pack_kernel<<<gpack, 256, 0, stream>>>(preds, gts, packP, packG);

    hipMemsetAsync(keys, 0xFF, (size_t)2 * BN * sizeof(unsigned), stream);
    hipMemsetAsync(out, 0, sizeof(float), stream);

    dim3 gmain(BATCH * QBLK, NCH, 2);
    chamfer_min_kernel<<<gmain, 256, 0, stream>>>(packP, packG, keys);

    finalize_kernel<<<2 * BN / 256, 256, 0, stream>>>(keys, packP, packG, out);
}

// Round 5
// 56.250 us; speedup vs baseline: 1.7926x; 1.0475x over previous
//
#include <hip/hip_runtime.h>

#define BATCH 4
#define NPTS  8192
#define BN    (BATCH * NPTS)
#define QPT   8                    // queries per thread
#define CH    128                  // candidate chunk size
#define NCH   (NPTS / CH)          // 64 chunks
#define QBLK  (NPTS / (256 * QPT)) // 4 query-blocks per batch

// order-preserving float <-> uint for unsigned atomicMin
__device__ __forceinline__ unsigned fkey(float f) {
    unsigned u = __float_as_uint(f);
    return u ^ (unsigned)(((int)u >> 31) | 0x80000000);
}
__device__ __forceinline__ float funkey(unsigned k) {
    unsigned u = k ^ ((k & 0x80000000u) ? 0x80000000u : 0xFFFFFFFFu);
    return __uint_as_float(u);
}

// ---- main: fused pack + LDS-broadcast min, atomicMin(min + qsq) -----------
// grid: (BATCH*QBLK, NCH, 2); block: 256
// keys layout: [dir][B*N], encoded min over candidates of |q-c|^2
__global__ void __launch_bounds__(256)
chamfer_min_kernel(const float* __restrict__ preds,
                   const float* __restrict__ gts,
                   unsigned* __restrict__ keys) {
    __shared__ float4 cl[CH];        // packed {-2x,-2y,-2z,|c|^2}
    __shared__ float  craw[CH * 3];  // raw staging

    const int dir   = blockIdx.z;   // 0: queries=preds, cand=gts ; 1: swapped
    const int chunk = blockIdx.y;
    const int b     = blockIdx.x / QBLK;
    const int qb    = blockIdx.x % QBLK;
    const int t     = threadIdx.x;

    const float* __restrict__ q_src = dir ? gts : preds;
    const float* __restrict__ c_src = dir ? preds : gts;

    // stage raw candidate chunk (CH*3 = 384 floats), coalesced
    const float* __restrict__ crawg = c_src + (size_t)3 * (b * NPTS + chunk * CH);
    craw[t] = crawg[t];
    if (t < CH * 3 - 256)
        craw[256 + t] = crawg[256 + t];

    // load this thread's 8 raw queries
    const int q0 = b * NPTS + qb * (256 * QPT) + t;
    float qx[QPT], qy[QPT], qz[QPT], m[QPT];
#pragma unroll
    for (int k = 0; k < QPT; ++k) {
        const float* __restrict__ qs = q_src + (size_t)3 * (q0 + k * 256);
        qx[k] = qs[0]; qy[k] = qs[1]; qz[k] = qs[2];
        m[k] = 1e30f;
    }

    __syncthreads();
    if (t < CH) {
        float x = craw[3 * t], y = craw[3 * t + 1], z = craw[3 * t + 2];
        cl[t] = make_float4(-2.0f * x, -2.0f * y, -2.0f * z,
                            x * x + y * y + z * z);
    }
    __syncthreads();

#pragma unroll 2
    for (int c = 0; c < CH; c += 2) {
        float4 c0 = cl[c];        // uniform address -> LDS broadcast
        float4 c1 = cl[c + 1];
#pragma unroll
        for (int k = 0; k < QPT; ++k) {
            float d0 = fmaf(qx[k], c0.x, fmaf(qy[k], c0.y, fmaf(qz[k], c0.z, c0.w)));
            float d1 = fmaf(qx[k], c1.x, fmaf(qy[k], c1.y, fmaf(qz[k], c1.z, c1.w)));
            m[k] = fminf(m[k], fminf(d0, d1));   // -> v_min3_f32
        }
    }

    unsigned* __restrict__ kout = keys + (size_t)dir * BN;
#pragma unroll
    for (int k = 0; k < QPT; ++k) {
        float qsq = fmaf(qx[k], qx[k], fmaf(qy[k], qy[k], qz[k] * qz[k]));
        atomicMin(&kout[q0 + k * 256], fkey(m[k] + qsq));
    }
}

// ---- finalize: decode key, global sum -------------------------------------
// grid: 2*B*N/256 = 256 blocks
__global__ void __launch_bounds__(256)
finalize_kernel(const unsigned* __restrict__ keys, float* __restrict__ out) {
    __shared__ float red[4];
    const int idx = blockIdx.x * 256 + threadIdx.x;   // [0, 2*B*N)

    float val = funkey(keys[idx]);

#pragma unroll
    for (int off = 32; off > 0; off >>= 1)
        val += __shfl_down(val, off, 64);

    const int wave = threadIdx.x >> 6;
    const int lane = threadIdx.x & 63;
    if (lane == 0) red[wave] = val;
    __syncthreads();
    if (threadIdx.x == 0)
        atomicAdd(out, red[0] + red[1] + red[2] + red[3]);
}

extern "C" void kernel_launch(void* const* d_in, const int* in_sizes, int n_in,
                              void* d_out, int out_size, void* d_ws, size_t ws_size,
                              hipStream_t stream) {
    const float* preds = (const float*)d_in[0];
    const float* gts   = (const float*)d_in[1];
    float* out = (float*)d_out;

    unsigned* keys = (unsigned*)d_ws;   // 256 KB

    hipMemsetAsync(keys, 0xFF, (size_t)2 * BN * sizeof(unsigned), stream);
    hipMemsetAsync(out, 0, sizeof(float), stream);

    dim3 gmain(BATCH * QBLK, NCH, 2);
    chamfer_min_kernel<<<gmain, 256, 0, stream>>>(preds, gts, keys);

    finalize_kernel<<<2 * BN / 256, 256, 0, stream>>>(keys, out);
}